// Round 18
// baseline (561.073 us; speedup 1.0000x reference)
//
#include <hip/hip_runtime.h>

#define N_NODES 100000
#define N_EDGES 3200000
#define F_X 24
#define F_S 8
#define D_IN 32   // F_X + F_S
#define H_DIM 64
#define F_OUT 32

#define NBKT2 782                // half-buckets (bkt = dst>>7, 128 nodes each)
#define HPB 128                  // nodes per half-bucket
#define BCAP_H 4608              // per-half capacity (mean 4092 + ~8 sigma)
#define P1_THREADS 1024
#define P1_EPT 16                // edges per thread in partition
#define P1_EPB (P1_THREADS * P1_EPT)                  // 16384 edges per block
#define P1_BLOCKS ((N_EDGES + P1_EPB - 1) / P1_EPB)   // 196
#define MLP_BLOCKS ((N_NODES + 255) / 256)            // 391 (256 nodes/block)
#define P2_THREADS 512
#define OFFS_ROW 783             // 782 bucket bases + total
#define SRC_SPLIT 50000          // src phase split for y L2 residency

// float -> bf16 (round-to-nearest-even), returns low 16 bits
__device__ __forceinline__ unsigned bf16_rne(float f) {
    unsigned u = __float_as_uint(f);
    return (u + 0x7fffu + ((u >> 16) & 1u)) >> 16;
}

// ---------------------------------------------------------------------------
// Fused kernel.
//  blocks [0, P1_BLOCKS): edge partition (exact round-15 code).
//  blocks [P1_BLOCKS, +MLP_BLOCKS): node MLP, 8-lane groups x 2 nodes/lane
//    (halves weight ds_reads per node); scalar features folded into bias.
//  __launch_bounds__(1024, 4): min 4 waves/EU -> VGPR cap 128 (not the
//  default 64) so the B=2 MLP working set stays in registers. Rounds 13/14
//  showed the default cap forces catastrophic scratch spills; verification
//  signal this round: fused WRITE_SIZE must be ~19MB, not hundreds of MB.
// ---------------------------------------------------------------------------
__global__ __launch_bounds__(P1_THREADS, 4) void fused_mlp_p1(
    const float* __restrict__ x, const float* __restrict__ scalars,
    const float* __restrict__ W1, const float* __restrict__ b1,
    const float* __restrict__ W2, const float* __restrict__ b2,
    unsigned* __restrict__ y,
    const int* __restrict__ ei,
    unsigned* __restrict__ bbuf,     // [P1_BLOCKS * P1_EPB] sorted packed edges
    int* __restrict__ offs_g)        // [P1_BLOCKS][OFFS_ROW]
{
    __shared__ __align__(16) unsigned char smem[71928];
    const int tid = threadIdx.x;

    if (blockIdx.x < P1_BLOCKS) {
        unsigned* sSE  = (unsigned*)smem;            // 65536 B
        int* cnt       = (int*)(smem + 65536);       // 3128 B (782)
        int* runoff    = (int*)(smem + 68664);       // 3132 B (783)
        int* wsum      = (int*)(smem + 71796);       // 64 B (16)

        const int nbase = blockIdx.x * P1_EPB;
        const int nThis = min(P1_EPB, N_EDGES - nbase);

        for (int i = tid; i < NBKT2; i += P1_THREADS) cnt[i] = 0;
        __syncthreads();

        unsigned pk[P1_EPT];
        int meta[P1_EPT];                 // bkt (10b) | rank<<10 (14b)
        #pragma unroll
        for (int k = 0; k < P1_EPT; ++k) {
            const int idx = tid + k * P1_THREADS;   // coalesced stream
            if (idx < nThis) {
                const int e = nbase + idx;
                const int src = ei[e];
                const int dst = ei[N_EDGES + e];
                const int bkt = dst >> 7;
                const int rank = atomicAdd(&cnt[bkt], 1);
                pk[k]   = (unsigned)src | ((unsigned)(dst & 127) << 17);
                meta[k] = bkt | (rank << 10);
            } else {
                meta[k] = -1;
            }
        }
        __syncthreads();

        // exclusive scan of 782 counts (16 wave-scans + combine)
        const int lane = tid & 63, wid = tid >> 6;
        const int cval = (tid < NBKT2) ? cnt[tid] : 0;
        int a = cval;
        #pragma unroll
        for (int off = 1; off < 64; off <<= 1) {
            const int u = __shfl_up(a, off, 64);
            if (lane >= off) a += u;
        }
        if (lane == 63) wsum[wid] = a;
        __syncthreads();
        if (tid == 0) {
            int r = 0;
            #pragma unroll
            for (int w = 0; w < 16; ++w) { const int t = wsum[w]; wsum[w] = r; r += t; }
        }
        __syncthreads();
        if (tid <= NBKT2) {
            const int bse = wsum[wid] + a - cval;   // tid==NBKT2 -> total == nThis
            runoff[tid] = bse;
            offs_g[blockIdx.x * OFFS_ROW + tid] = bse;
        }
        __syncthreads();

        // scatter into LDS in bucket-sorted order
        #pragma unroll
        for (int k = 0; k < P1_EPT; ++k) {
            if (meta[k] >= 0)
                sSE[runoff[meta[k] & 1023] + (meta[k] >> 10)] = pk[k];
        }
        __syncthreads();

        // stream out: perfectly coalesced uint4
        const uint4* s4 = (const uint4*)sSE;
        uint4* b4 = (uint4*)(bbuf + (size_t)blockIdx.x * P1_EPB);
        for (int i = tid; i < (nThis >> 2); i += P1_THREADS) b4[i] = s4[i];
    } else {
        // ---------------- mlp: 8-lane groups, 2 nodes per lane ---------------
        float* sW1  = (float*)smem;                  // 8192 B  [k][l]
        float* sW2  = (float*)(smem + 8192);         // 8192 B  [l][j]
        float* sb1f = (float*)(smem + 16384);        // 256 B (scalar-folded bias)
        float* sb2  = (float*)(smem + 16640);        // 128 B
        float* ss   = (float*)(smem + 16768);        // 32 B

        for (int i = tid; i < D_IN * H_DIM; i += P1_THREADS) sW1[i] = W1[i];
        for (int i = tid; i < H_DIM * F_OUT; i += P1_THREADS) sW2[i] = W2[i];
        if (tid < F_OUT)  sb2[tid] = b2[tid];
        if (tid < F_S)    ss[tid]  = scalars[tid];
        __syncthreads();
        // fold scalar features into layer-1 bias (they are node-uniform)
        if (tid < H_DIM) {
            float acc = b1[tid];
            #pragma unroll
            for (int j = 0; j < F_S; ++j)
                acc += ss[j] * sW1[(F_X + j) * H_DIM + tid];
            sb1f[tid] = acc;
        }
        __syncthreads();

        const int mb = blockIdx.x - P1_BLOCKS;
        const int g = tid >> 3;          // group 0..127 (2 nodes each)
        const int c = tid & 7;           // lane owns hid[c*8..+8), out[c*4..+4)
        const int v0 = mb * 256 + g * 2;
        const int v1 = v0 + 1;
        const bool val0 = v0 < N_NODES, val1 = v1 < N_NODES;
        const int r0 = val0 ? v0 : (N_NODES - 1);
        const int r1 = val1 ? v1 : (N_NODES - 1);

        // layer 1 (k = 0..23 only; scalars folded into bias)
        float hid[2][8];
        {
            const float4* bb = (const float4*)(sb1f + c * 8);
            const float4 t0 = bb[0], t1 = bb[1];
            hid[0][0] = t0.x; hid[0][1] = t0.y; hid[0][2] = t0.z; hid[0][3] = t0.w;
            hid[0][4] = t1.x; hid[0][5] = t1.y; hid[0][6] = t1.z; hid[0][7] = t1.w;
            #pragma unroll
            for (int l = 0; l < 8; ++l) hid[1][l] = hid[0][l];
        }
        const float4* x40 = (const float4*)(x + (size_t)r0 * F_X);
        const float4* x41 = (const float4*)(x + (size_t)r1 * F_X);
        #pragma unroll
        for (int kc = 0; kc < 6; ++kc) {
            const float4 h0 = x40[kc];
            const float4 h1 = x41[kc];
            const float hk0[4] = {h0.x, h0.y, h0.z, h0.w};
            const float hk1[4] = {h1.x, h1.y, h1.z, h1.w};
            #pragma unroll
            for (int kk = 0; kk < 4; ++kk) {
                const float4* wr = (const float4*)(sW1 + (kc * 4 + kk) * H_DIM + c * 8);
                const float4 w0 = wr[0], w1 = wr[1];
                hid[0][0] = fmaf(hk0[kk], w0.x, hid[0][0]);
                hid[0][1] = fmaf(hk0[kk], w0.y, hid[0][1]);
                hid[0][2] = fmaf(hk0[kk], w0.z, hid[0][2]);
                hid[0][3] = fmaf(hk0[kk], w0.w, hid[0][3]);
                hid[0][4] = fmaf(hk0[kk], w1.x, hid[0][4]);
                hid[0][5] = fmaf(hk0[kk], w1.y, hid[0][5]);
                hid[0][6] = fmaf(hk0[kk], w1.z, hid[0][6]);
                hid[0][7] = fmaf(hk0[kk], w1.w, hid[0][7]);
                hid[1][0] = fmaf(hk1[kk], w0.x, hid[1][0]);
                hid[1][1] = fmaf(hk1[kk], w0.y, hid[1][1]);
                hid[1][2] = fmaf(hk1[kk], w0.z, hid[1][2]);
                hid[1][3] = fmaf(hk1[kk], w0.w, hid[1][3]);
                hid[1][4] = fmaf(hk1[kk], w1.x, hid[1][4]);
                hid[1][5] = fmaf(hk1[kk], w1.y, hid[1][5]);
                hid[1][6] = fmaf(hk1[kk], w1.z, hid[1][6]);
                hid[1][7] = fmaf(hk1[kk], w1.w, hid[1][7]);
            }
        }
        #pragma unroll
        for (int i = 0; i < 2; ++i)
            #pragma unroll
            for (int l = 0; l < 8; ++l) hid[i][l] = fmaxf(hid[i][l], 0.0f);

        // layer 2: lane owns out j in [c*4, c*4+4); pull hid chunks via shfl_xor
        float op[2][4] = {{0.f, 0.f, 0.f, 0.f}, {0.f, 0.f, 0.f, 0.f}};
        #pragma unroll
        for (int d = 0; d < 8; ++d) {
            const int cc = c ^ d;
            #pragma unroll
            for (int ll = 0; ll < 8; ++ll) {
                float hv0 = hid[0][ll], hv1 = hid[1][ll];
                if (d) { hv0 = __shfl_xor(hv0, d); hv1 = __shfl_xor(hv1, d); }
                const float4 w = *(const float4*)(sW2 + (cc * 8 + ll) * F_OUT + c * 4);
                op[0][0] = fmaf(hv0, w.x, op[0][0]);
                op[0][1] = fmaf(hv0, w.y, op[0][1]);
                op[0][2] = fmaf(hv0, w.z, op[0][2]);
                op[0][3] = fmaf(hv0, w.w, op[0][3]);
                op[1][0] = fmaf(hv1, w.x, op[1][0]);
                op[1][1] = fmaf(hv1, w.y, op[1][1]);
                op[1][2] = fmaf(hv1, w.z, op[1][2]);
                op[1][3] = fmaf(hv1, w.w, op[1][3]);
            }
        }
        const float4 bo = *(const float4*)(sb2 + c * 4);
        op[0][0] += bo.x; op[0][1] += bo.y; op[0][2] += bo.z; op[0][3] += bo.w;
        op[1][0] += bo.x; op[1][1] += bo.y; op[1][2] += bo.z; op[1][3] += bo.w;

        // pack 4 f32 -> 2 uints (bf16 pairs); 8 lanes x 8B = full 64B row
        if (val0) {
            uint2 p;
            p.x = bf16_rne(op[0][0]) | (bf16_rne(op[0][1]) << 16);
            p.y = bf16_rne(op[0][2]) | (bf16_rne(op[0][3]) << 16);
            *(uint2*)(y + (size_t)v0 * 16 + c * 2) = p;
        }
        if (val1) {
            uint2 p;
            p.x = bf16_rne(op[1][0]) | (bf16_rne(op[1][1]) << 16);
            p.y = bf16_rne(op[1][2]) | (bf16_rne(op[1][3]) << 16);
            *(uint2*)(y + (size_t)v1 * 16 + c * 2) = p;
        }
    }
}

// ---------------------------------------------------------------------------
// Kernel 2: per-half-bucket aggregation (EXACT round-15 code — proven best).
//   a) stage this block's exact segments into sE: 2 THREADS PER SEGMENT
//   b) counting sort into 256 bins = localDst*2 + (src>=SRC_SPLIT)
//   c) phased gather (low-src bins, barrier, high-src bins), depth-4 pinned
//   d) registers -> global out
//  NOTE: round 16 (quarter buckets) and round 17 (depth-8) both regressed.
// ---------------------------------------------------------------------------
__global__ __launch_bounds__(P2_THREADS) void p2_aggregate(
    const unsigned* __restrict__ bbuf,
    const int* __restrict__ offs_g,
    const unsigned* __restrict__ y,
    float* __restrict__ out)
{
    __shared__ unsigned sE[BCAP_H];        // 18 KB staged edges
    __shared__ unsigned sS[BCAP_H];        // 18 KB sorted src ids
    __shared__ int segsrc[P1_BLOCKS];      // 784 B
    __shared__ int segoff[P1_BLOCKS + 1];  // 788 B
    __shared__ int cnt[2 * HPB];           // 1 KB (doubles as cursor)
    __shared__ int cbase[2 * HPB + 1];     // 1028 B
    __shared__ int wtmp[16];

    const int tid = threadIdx.x;
    const int bkt = blockIdx.x;            // 0..781
    const int lane = tid & 63, wid = tid >> 6;

    // ---- segment table + exclusive scan of 196 lengths -> segoff ----
    int slen = 0;
    if (tid < P1_BLOCKS) {
        const int o0 = offs_g[tid * OFFS_ROW + bkt];
        slen = offs_g[tid * OFFS_ROW + bkt + 1] - o0;
        segsrc[tid] = o0;
    }
    int sa = slen;
    #pragma unroll
    for (int off = 1; off < 64; off <<= 1) {
        const int u = __shfl_up(sa, off, 64);
        if (lane >= off) sa += u;
    }
    if (lane == 63 && wid < 4) wtmp[wid] = sa;
    if (tid < 2 * HPB) cnt[tid] = 0;
    __syncthreads();
    if (tid == 0) {
        int r = 0;
        #pragma unroll
        for (int w = 0; w < 4; ++w) { const int t = wtmp[w]; wtmp[w] = r; r += t; }
        segoff[P1_BLOCKS] = (r < BCAP_H) ? r : BCAP_H;
    }
    __syncthreads();
    if (tid < P1_BLOCKS) segoff[tid] = wtmp[wid] + sa - slen;
    __syncthreads();

    const int nE = segoff[P1_BLOCKS];

    // a) stage: 2 threads per segment, interleaved copy (no binary search)
    {
        const int s = tid >> 1;
        if (s < P1_BLOCKS) {
            const int d0 = segoff[s];
            const int len = ((s + 1 <= P1_BLOCKS) ? segoff[s + 1] : nE) - d0;
            const unsigned* gp = bbuf + (size_t)s * P1_EPB + segsrc[s];
            for (int j = (tid & 1); j < len; j += 2) {
                const int dp = d0 + j;
                if (dp < BCAP_H) sE[dp] = gp[j];
            }
        }
    }
    __syncthreads();

    // b1) count per bin (localDst*2 + srcHalf)
    for (int i = tid; i < nE; i += P2_THREADS) {
        const unsigned w = sE[i];
        const int bin = (int)((w >> 17) & 127u) * 2 + ((w & 0x1FFFFu) >= SRC_SPLIT);
        atomicAdd(&cnt[bin], 1);
    }
    __syncthreads();

    // b2) exclusive scan of 256 bins
    int vcnt = 0, a2 = 0;
    if (tid < 2 * HPB) {
        vcnt = cnt[tid];
        a2 = vcnt;
        #pragma unroll
        for (int off = 1; off < 64; off <<= 1) {
            const int u = __shfl_up(a2, off, 64);
            if (lane >= off) a2 += u;
        }
        if (lane == 63) wtmp[8 + wid] = a2;
    }
    __syncthreads();
    if (tid == 0) {
        int r = 0;
        #pragma unroll
        for (int w = 0; w < 4; ++w) { const int t = wtmp[8 + w]; wtmp[8 + w] = r; r += t; }
        cbase[2 * HPB] = r;
    }
    __syncthreads();
    if (tid < 2 * HPB) cbase[tid] = wtmp[8 + wid] + a2 - vcnt;
    __syncthreads();
    if (tid < 2 * HPB) cnt[tid] = cbase[tid];   // cursor
    __syncthreads();

    // b3) scatter src ids into bin-sorted order
    for (int i = tid; i < nE; i += P2_THREADS) {
        const unsigned w = sE[i];
        const unsigned src = w & 0x1FFFFu;
        const int bin = (int)((w >> 17) & 127u) * 2 + (src >= SRC_SPLIT);
        const int pos = atomicAdd(&cnt[bin], 1);
        if (pos < BCAP_H) sS[pos] = src;
    }
    __syncthreads();

    // c) phased gather: 4-lane group g owns node g; lane c = uint4 chunk c
    const int g = tid >> 2;     // 0..127
    const int c = tid & 3;

    float acc[8];
    #pragma unroll
    for (int k = 0; k < 8; ++k) acc[k] = 0.0f;

    #pragma unroll
    for (int ph = 0; ph < 2; ++ph) {
        int beg = cbase[2 * g + ph];
        int end = cbase[2 * g + ph + 1];
        if (beg > BCAP_H) beg = BCAP_H;
        if (end > BCAP_H) end = BCAP_H;

        int i = beg;
        for (; i + 4 <= end; i += 4) {
            unsigned s[4];
            #pragma unroll
            for (int j = 0; j < 4; ++j) s[j] = sS[i + j];

            uint4 q[4];
            #pragma unroll
            for (int j = 0; j < 4; ++j)
                q[j] = reinterpret_cast<const uint4*>(y + (size_t)s[j] * 16)[c];

            __builtin_amdgcn_sched_barrier(0);   // keep 4 loads in flight

            #pragma unroll
            for (int j = 0; j < 4; ++j) {
                const unsigned qq[4] = {q[j].x, q[j].y, q[j].z, q[j].w};
                #pragma unroll
                for (int k = 0; k < 4; ++k) {
                    acc[2 * k + 0] += __uint_as_float(qq[k] << 16);
                    acc[2 * k + 1] += __uint_as_float(qq[k] & 0xFFFF0000u);
                }
            }
        }
        for (; i < end; ++i) {
            const uint4 q = reinterpret_cast<const uint4*>(y + (size_t)sS[i] * 16)[c];
            const unsigned qq[4] = {q.x, q.y, q.z, q.w};
            #pragma unroll
            for (int k = 0; k < 4; ++k) {
                acc[2 * k + 0] += __uint_as_float(qq[k] << 16);
                acc[2 * k + 1] += __uint_as_float(qq[k] & 0xFFFF0000u);
            }
        }
        if (ph == 0) __syncthreads();   // block-wide phase boundary
    }

    // d) write out: lane owns floats [c*8, c*8+8) of row v
    const int v = bkt * HPB + g;
    if (v < N_NODES) {
        float4* op = reinterpret_cast<float4*>(out + (size_t)v * F_OUT + c * 8);
        op[0] = make_float4(acc[0], acc[1], acc[2], acc[3]);
        op[1] = make_float4(acc[4], acc[5], acc[6], acc[7]);
    }
}

extern "C" void kernel_launch(void* const* d_in, const int* in_sizes, int n_in,
                              void* d_out, int out_size, void* d_ws, size_t ws_size,
                              hipStream_t stream) {
    const float* x       = (const float*)d_in[0];
    const float* scalars = (const float*)d_in[1];
    const int*   ei      = (const int*)d_in[2];
    const float* W1      = (const float*)d_in[3];
    const float* b1      = (const float*)d_in[4];
    const float* W2      = (const float*)d_in[5];
    const float* b2      = (const float*)d_in[6];
    float* out = (float*)d_out;

    // Workspace layout (16B aligned), total ~19.9 MB
    char* ws = (char*)d_ws;
    unsigned* y      = (unsigned*)ws;                    //  6,400,000 B
    unsigned* bbuf   = (unsigned*)(ws + 6400000);        // 12,845,056 B (196*16384*4)
    int*      offs_g = (int*)(ws + 19245056);            //    613,872 B (196*783*4)

    // 1) fused: edge partition (blocks 0..195) + node MLP (blocks 196..586)
    fused_mlp_p1<<<P1_BLOCKS + MLP_BLOCKS, P1_THREADS, 0, stream>>>(
        x, scalars, W1, b1, W2, b2, y, ei, bbuf, offs_g);

    // 2) per-half-bucket stage + sort + phased gather + write (782 blocks)
    p2_aggregate<<<NBKT2, P2_THREADS, 0, stream>>>(bbuf, offs_g, y, out);
}

// Round 19
// 81.111 us; speedup vs baseline: 6.9173x; 6.9173x over previous
//
#include <hip/hip_runtime.h>

#define N_NODES 100000
#define N_EDGES 3200000
#define F_X 24
#define F_S 8
#define D_IN 32   // F_X + F_S
#define H_DIM 64
#define F_OUT 32

#define NBKT2 782                // half-buckets (bkt = dst>>7, 128 nodes each)
#define HPB 128                  // nodes per half-bucket
#define BCAP_H 4608              // per-half capacity (mean 4092 + ~8 sigma)
#define P1_THREADS 1024
#define P1_EPT 16                // edges per thread in partition
#define P1_EPB (P1_THREADS * P1_EPT)                  // 16384 edges per block
#define P1_BLOCKS ((N_EDGES + P1_EPB - 1) / P1_EPB)   // 196
#define MLP_BLOCKS ((N_NODES + 255) / 256)            // 391 (256 nodes/block)
#define P2_THREADS 512
#define OFFS_ROW 783             // 782 bucket bases + total
#define SRC_SPLIT 50000          // src phase split for y L2 residency

// float -> bf16 (round-to-nearest-even), returns low 16 bits
__device__ __forceinline__ unsigned bf16_rne(float f) {
    unsigned u = __float_as_uint(f);
    return (u + 0x7fffu + ((u >> 16) & 1u)) >> 16;
}

// ---------------------------------------------------------------------------
// Fused kernel (round-15 proven code; NO min-waves launch bound).
//  blocks [0, P1_BLOCKS): stage 16K edges, LDS counting-sort by the 782
//    half-buckets, write sorted block contiguously + its 783-entry offset row.
//  blocks [P1_BLOCKS, +MLP_BLOCKS): node MLP (4 lanes/node) -> bf16 y;
//    scalar features folded into layer-1 bias.
//  HISTORY: 8-lane x 2-node MLP spills ~780MB scratch at the allocator's
//  pinned 64-VGPR choice under ALL launch-bound settings (r13/r14/r18).
//  Quarter-buckets (r16) and depth-8 gather (r17) both regressed p2.
// ---------------------------------------------------------------------------
__global__ __launch_bounds__(P1_THREADS) void fused_mlp_p1(
    const float* __restrict__ x, const float* __restrict__ scalars,
    const float* __restrict__ W1, const float* __restrict__ b1,
    const float* __restrict__ W2, const float* __restrict__ b2,
    unsigned* __restrict__ y,
    const int* __restrict__ ei,
    unsigned* __restrict__ bbuf,     // [P1_BLOCKS * P1_EPB] sorted packed edges
    int* __restrict__ offs_g)        // [P1_BLOCKS][OFFS_ROW]
{
    __shared__ __align__(16) unsigned char smem[71928];
    const int tid = threadIdx.x;

    if (blockIdx.x < P1_BLOCKS) {
        unsigned* sSE  = (unsigned*)smem;            // 65536 B
        int* cnt       = (int*)(smem + 65536);       // 3128 B (782)
        int* runoff    = (int*)(smem + 68664);       // 3132 B (783)
        int* wsum      = (int*)(smem + 71796);       // 64 B (16)

        const int nbase = blockIdx.x * P1_EPB;
        const int nThis = min(P1_EPB, N_EDGES - nbase);

        for (int i = tid; i < NBKT2; i += P1_THREADS) cnt[i] = 0;
        __syncthreads();

        unsigned pk[P1_EPT];
        int meta[P1_EPT];                 // bkt (10b) | rank<<10 (14b)
        #pragma unroll
        for (int k = 0; k < P1_EPT; ++k) {
            const int idx = tid + k * P1_THREADS;   // coalesced stream
            if (idx < nThis) {
                const int e = nbase + idx;
                const int src = ei[e];
                const int dst = ei[N_EDGES + e];
                const int bkt = dst >> 7;
                const int rank = atomicAdd(&cnt[bkt], 1);
                pk[k]   = (unsigned)src | ((unsigned)(dst & 127) << 17);
                meta[k] = bkt | (rank << 10);
            } else {
                meta[k] = -1;
            }
        }
        __syncthreads();

        // exclusive scan of 782 counts (16 wave-scans + combine)
        const int lane = tid & 63, wid = tid >> 6;
        const int cval = (tid < NBKT2) ? cnt[tid] : 0;
        int a = cval;
        #pragma unroll
        for (int off = 1; off < 64; off <<= 1) {
            const int u = __shfl_up(a, off, 64);
            if (lane >= off) a += u;
        }
        if (lane == 63) wsum[wid] = a;
        __syncthreads();
        if (tid == 0) {
            int r = 0;
            #pragma unroll
            for (int w = 0; w < 16; ++w) { const int t = wsum[w]; wsum[w] = r; r += t; }
        }
        __syncthreads();
        if (tid <= NBKT2) {
            const int bse = wsum[wid] + a - cval;   // tid==NBKT2 -> total == nThis
            runoff[tid] = bse;
            offs_g[blockIdx.x * OFFS_ROW + tid] = bse;
        }
        __syncthreads();

        // scatter into LDS in bucket-sorted order
        #pragma unroll
        for (int k = 0; k < P1_EPT; ++k) {
            if (meta[k] >= 0)
                sSE[runoff[meta[k] & 1023] + (meta[k] >> 10)] = pk[k];
        }
        __syncthreads();

        // stream out: perfectly coalesced uint4
        const uint4* s4 = (const uint4*)sSE;
        uint4* b4 = (uint4*)(bbuf + (size_t)blockIdx.x * P1_EPB);
        for (int i = tid; i < (nThis >> 2); i += P1_THREADS) b4[i] = s4[i];
    } else {
        // ------------- mlp: 4 lanes per node (round-12 structure) ------------
        float* sW1  = (float*)smem;                  // 8192 B  [k][l]
        float* sW2  = (float*)(smem + 8192);         // 8192 B  [l][j]
        float* sb1f = (float*)(smem + 16384);        // 256 B (scalar-folded bias)
        float* sb2  = (float*)(smem + 16640);        // 128 B
        float* ss   = (float*)(smem + 16768);        // 32 B

        for (int i = tid; i < D_IN * H_DIM; i += P1_THREADS) sW1[i] = W1[i];
        for (int i = tid; i < H_DIM * F_OUT; i += P1_THREADS) sW2[i] = W2[i];
        if (tid < F_OUT)  sb2[tid] = b2[tid];
        if (tid < F_S)    ss[tid]  = scalars[tid];
        __syncthreads();
        // fold scalar features into layer-1 bias (they are node-uniform)
        if (tid < H_DIM) {
            float acc = b1[tid];
            #pragma unroll
            for (int j = 0; j < F_S; ++j)
                acc += ss[j] * sW1[(F_X + j) * H_DIM + tid];
            sb1f[tid] = acc;
        }
        __syncthreads();

        const int mb = blockIdx.x - P1_BLOCKS;
        const int v = mb * 256 + (tid >> 2);
        const int c = tid & 3;
        if (v >= N_NODES) return;

        // input row: 24 x-features only (scalars folded away)
        float h[F_X];
        const float4* xr = reinterpret_cast<const float4*>(x + (size_t)v * F_X);
        #pragma unroll
        for (int i = 0; i < F_X / 4; ++i) {
            float4 t = xr[i];
            h[i * 4 + 0] = t.x; h[i * 4 + 1] = t.y;
            h[i * 4 + 2] = t.z; h[i * 4 + 3] = t.w;
        }

        // layer 1: lane owns hid l in [c*16, c*16+16); k = 0..23
        float hid[16];
        {
            const float4* bb = reinterpret_cast<const float4*>(sb1f + c * 16);
            #pragma unroll
            for (int q = 0; q < 4; ++q) {
                const float4 t = bb[q];
                hid[q * 4 + 0] = t.x; hid[q * 4 + 1] = t.y;
                hid[q * 4 + 2] = t.z; hid[q * 4 + 3] = t.w;
            }
        }
        #pragma unroll
        for (int k = 0; k < F_X; ++k) {
            const float hk = h[k];
            const float4* wr = reinterpret_cast<const float4*>(sW1 + k * H_DIM + c * 16);
            #pragma unroll
            for (int q = 0; q < 4; ++q) {
                const float4 t = wr[q];
                hid[q * 4 + 0] = fmaf(hk, t.x, hid[q * 4 + 0]);
                hid[q * 4 + 1] = fmaf(hk, t.y, hid[q * 4 + 1]);
                hid[q * 4 + 2] = fmaf(hk, t.z, hid[q * 4 + 2]);
                hid[q * 4 + 3] = fmaf(hk, t.w, hid[q * 4 + 3]);
            }
        }
        #pragma unroll
        for (int l = 0; l < 16; ++l) hid[l] = fmaxf(hid[l], 0.0f);

        // layer 2: lane owns out j in [c*8, c*8+8); shfl hid chunks around
        float op[8];
        #pragma unroll
        for (int t = 0; t < 8; ++t) op[t] = 0.0f;

        #pragma unroll
        for (int d = 0; d < 4; ++d) {
            const int cc = c ^ d;
            float ht[16];
            if (d == 0) {
                #pragma unroll
                for (int t = 0; t < 16; ++t) ht[t] = hid[t];
            } else {
                #pragma unroll
                for (int t = 0; t < 16; ++t) ht[t] = __shfl_xor(hid[t], d);
            }
            const int lbase = cc * 16;
            #pragma unroll
            for (int ll = 0; ll < 16; ++ll) {
                const float hl = ht[ll];
                const float4* wr = reinterpret_cast<const float4*>(
                    sW2 + (lbase + ll) * F_OUT + c * 8);
                const float4 t0 = wr[0], t1 = wr[1];
                op[0] = fmaf(hl, t0.x, op[0]);
                op[1] = fmaf(hl, t0.y, op[1]);
                op[2] = fmaf(hl, t0.z, op[2]);
                op[3] = fmaf(hl, t0.w, op[3]);
                op[4] = fmaf(hl, t1.x, op[4]);
                op[5] = fmaf(hl, t1.y, op[5]);
                op[6] = fmaf(hl, t1.z, op[6]);
                op[7] = fmaf(hl, t1.w, op[7]);
            }
        }
        #pragma unroll
        for (int t = 0; t < 8; ++t) op[t] += sb2[c * 8 + t];

        // pack 8 f32 -> 4 uints (bf16 pairs), store 16B; 4 lanes = 64B row
        unsigned pk4[4];
        #pragma unroll
        for (int t = 0; t < 4; ++t)
            pk4[t] = bf16_rne(op[2 * t]) | (bf16_rne(op[2 * t + 1]) << 16);
        uint4* yr = reinterpret_cast<uint4*>(y + (size_t)v * 16 + c * 4);
        *yr = make_uint4(pk4[0], pk4[1], pk4[2], pk4[3]);
    }
}

// ---------------------------------------------------------------------------
// Kernel 2: per-half-bucket aggregation (round-15 code; one change: the
//   per-bin count is folded into the staging pass — the staging thread holds
//   each edge word in a register, so a separate sE count re-read is waste).
//   a) stage segments into sE (2 threads/segment) + count bins inline
//   b) exclusive scan of 256 bins; scatter src ids into bin-sorted order
//   c) phased gather (low-src bins, barrier, high-src bins), depth-4 pinned
//   d) registers -> global out
// ---------------------------------------------------------------------------
__global__ __launch_bounds__(P2_THREADS) void p2_aggregate(
    const unsigned* __restrict__ bbuf,
    const int* __restrict__ offs_g,
    const unsigned* __restrict__ y,
    float* __restrict__ out)
{
    __shared__ unsigned sE[BCAP_H];        // 18 KB staged edges
    __shared__ unsigned sS[BCAP_H];        // 18 KB sorted src ids
    __shared__ int segsrc[P1_BLOCKS];      // 784 B
    __shared__ int segoff[P1_BLOCKS + 1];  // 788 B
    __shared__ int cnt[2 * HPB];           // 1 KB (doubles as cursor)
    __shared__ int cbase[2 * HPB + 1];     // 1028 B
    __shared__ int wtmp[16];

    const int tid = threadIdx.x;
    const int bkt = blockIdx.x;            // 0..781
    const int lane = tid & 63, wid = tid >> 6;

    // ---- segment table + exclusive scan of 196 lengths -> segoff ----
    int slen = 0;
    if (tid < P1_BLOCKS) {
        const int o0 = offs_g[tid * OFFS_ROW + bkt];
        slen = offs_g[tid * OFFS_ROW + bkt + 1] - o0;
        segsrc[tid] = o0;
    }
    int sa = slen;
    #pragma unroll
    for (int off = 1; off < 64; off <<= 1) {
        const int u = __shfl_up(sa, off, 64);
        if (lane >= off) sa += u;
    }
    if (lane == 63 && wid < 4) wtmp[wid] = sa;
    if (tid < 2 * HPB) cnt[tid] = 0;
    __syncthreads();
    if (tid == 0) {
        int r = 0;
        #pragma unroll
        for (int w = 0; w < 4; ++w) { const int t = wtmp[w]; wtmp[w] = r; r += t; }
        segoff[P1_BLOCKS] = (r < BCAP_H) ? r : BCAP_H;
    }
    __syncthreads();
    if (tid < P1_BLOCKS) segoff[tid] = wtmp[wid] + sa - slen;
    __syncthreads();

    const int nE = segoff[P1_BLOCKS];

    // a) stage: 2 threads per segment, interleaved copy; count bins inline
    {
        const int s = tid >> 1;
        if (s < P1_BLOCKS) {
            const int d0 = segoff[s];
            const int len = ((s + 1 <= P1_BLOCKS) ? segoff[s + 1] : nE) - d0;
            const unsigned* gp = bbuf + (size_t)s * P1_EPB + segsrc[s];
            for (int j = (tid & 1); j < len; j += 2) {
                const int dp = d0 + j;
                if (dp < BCAP_H) {
                    const unsigned w = gp[j];
                    sE[dp] = w;
                    const int bin = (int)((w >> 17) & 127u) * 2
                                  + ((w & 0x1FFFFu) >= SRC_SPLIT);
                    atomicAdd(&cnt[bin], 1);
                }
            }
        }
    }
    __syncthreads();

    // b2) exclusive scan of 256 bins
    int vcnt = 0, a2 = 0;
    if (tid < 2 * HPB) {
        vcnt = cnt[tid];
        a2 = vcnt;
        #pragma unroll
        for (int off = 1; off < 64; off <<= 1) {
            const int u = __shfl_up(a2, off, 64);
            if (lane >= off) a2 += u;
        }
        if (lane == 63) wtmp[8 + wid] = a2;
    }
    __syncthreads();
    if (tid == 0) {
        int r = 0;
        #pragma unroll
        for (int w = 0; w < 4; ++w) { const int t = wtmp[8 + w]; wtmp[8 + w] = r; r += t; }
        cbase[2 * HPB] = r;
    }
    __syncthreads();
    if (tid < 2 * HPB) cbase[tid] = wtmp[8 + wid] + a2 - vcnt;
    __syncthreads();
    if (tid < 2 * HPB) cnt[tid] = cbase[tid];   // cursor
    __syncthreads();

    // b3) scatter src ids into bin-sorted order
    for (int i = tid; i < nE; i += P2_THREADS) {
        const unsigned w = sE[i];
        const unsigned src = w & 0x1FFFFu;
        const int bin = (int)((w >> 17) & 127u) * 2 + (src >= SRC_SPLIT);
        const int pos = atomicAdd(&cnt[bin], 1);
        if (pos < BCAP_H) sS[pos] = src;
    }
    __syncthreads();

    // c) phased gather: 4-lane group g owns node g; lane c = uint4 chunk c
    const int g = tid >> 2;     // 0..127
    const int c = tid & 3;

    float acc[8];
    #pragma unroll
    for (int k = 0; k < 8; ++k) acc[k] = 0.0f;

    #pragma unroll
    for (int ph = 0; ph < 2; ++ph) {
        int beg = cbase[2 * g + ph];
        int end = cbase[2 * g + ph + 1];
        if (beg > BCAP_H) beg = BCAP_H;
        if (end > BCAP_H) end = BCAP_H;

        int i = beg;
        for (; i + 4 <= end; i += 4) {
            unsigned s[4];
            #pragma unroll
            for (int j = 0; j < 4; ++j) s[j] = sS[i + j];

            uint4 q[4];
            #pragma unroll
            for (int j = 0; j < 4; ++j)
                q[j] = reinterpret_cast<const uint4*>(y + (size_t)s[j] * 16)[c];

            __builtin_amdgcn_sched_barrier(0);   // keep 4 loads in flight

            #pragma unroll
            for (int j = 0; j < 4; ++j) {
                const unsigned qq[4] = {q[j].x, q[j].y, q[j].z, q[j].w};
                #pragma unroll
                for (int k = 0; k < 4; ++k) {
                    acc[2 * k + 0] += __uint_as_float(qq[k] << 16);
                    acc[2 * k + 1] += __uint_as_float(qq[k] & 0xFFFF0000u);
                }
            }
        }
        for (; i < end; ++i) {
            const uint4 q = reinterpret_cast<const uint4*>(y + (size_t)sS[i] * 16)[c];
            const unsigned qq[4] = {q.x, q.y, q.z, q.w};
            #pragma unroll
            for (int k = 0; k < 4; ++k) {
                acc[2 * k + 0] += __uint_as_float(qq[k] << 16);
                acc[2 * k + 1] += __uint_as_float(qq[k] & 0xFFFF0000u);
            }
        }
        if (ph == 0) __syncthreads();   // block-wide phase boundary
    }

    // d) write out: lane owns floats [c*8, c*8+8) of row v
    const int v = bkt * HPB + g;
    if (v < N_NODES) {
        float4* op = reinterpret_cast<float4*>(out + (size_t)v * F_OUT + c * 8);
        op[0] = make_float4(acc[0], acc[1], acc[2], acc[3]);
        op[1] = make_float4(acc[4], acc[5], acc[6], acc[7]);
    }
}

extern "C" void kernel_launch(void* const* d_in, const int* in_sizes, int n_in,
                              void* d_out, int out_size, void* d_ws, size_t ws_size,
                              hipStream_t stream) {
    const float* x       = (const float*)d_in[0];
    const float* scalars = (const float*)d_in[1];
    const int*   ei      = (const int*)d_in[2];
    const float* W1      = (const float*)d_in[3];
    const float* b1      = (const float*)d_in[4];
    const float* W2      = (const float*)d_in[5];
    const float* b2      = (const float*)d_in[6];
    float* out = (float*)d_out;

    // Workspace layout (16B aligned), total ~19.9 MB
    char* ws = (char*)d_ws;
    unsigned* y      = (unsigned*)ws;                    //  6,400,000 B
    unsigned* bbuf   = (unsigned*)(ws + 6400000);        // 12,845,056 B (196*16384*4)
    int*      offs_g = (int*)(ws + 19245056);            //    613,872 B (196*783*4)

    // 1) fused: edge partition (blocks 0..195) + node MLP (blocks 196..586)
    fused_mlp_p1<<<P1_BLOCKS + MLP_BLOCKS, P1_THREADS, 0, stream>>>(
        x, scalars, W1, b1, W2, b2, y, ei, bbuf, offs_g);

    // 2) per-half-bucket stage + sort + phased gather + write (782 blocks)
    p2_aggregate<<<NBKT2, P2_THREADS, 0, stream>>>(bbuf, offs_g, y, out);
}

// Round 20
// 79.960 us; speedup vs baseline: 7.0169x; 1.0144x over previous
//
#include <hip/hip_runtime.h>

#define N_NODES 100000
#define N_EDGES 3200000
#define F_X 24
#define F_S 8
#define D_IN 32   // F_X + F_S
#define H_DIM 64
#define F_OUT 32

#define NBKT2 782                // half-buckets (bkt = dst>>7, 128 nodes each)
#define HPB 128                  // nodes per half-bucket
#define BCAP_H 4608              // per-half capacity (mean 4092 + ~8 sigma)
#define P1_THREADS 1024
#define P1_EPT 16                // edges per thread in partition
#define P1_EPB (P1_THREADS * P1_EPT)                  // 16384 edges per block
#define P1_BLOCKS ((N_EDGES + P1_EPB - 1) / P1_EPB)   // 196
#define MLP_BLOCKS ((N_NODES + 255) / 256)            // 391 (256 nodes/block)
#define P2_THREADS 512
#define OFFS_ROW 783             // 782 bucket bases + total
#define SRC_SPLIT 50000          // src phase split for y L2 residency

// float -> bf16 (round-to-nearest-even), returns low 16 bits
__device__ __forceinline__ unsigned bf16_rne(float f) {
    unsigned u = __float_as_uint(f);
    return (u + 0x7fffu + ((u >> 16) & 1u)) >> 16;
}

// ---------------------------------------------------------------------------
// Fused kernel.
//  blocks [0, P1_BLOCKS): edge partition (round-15 proven code, unchanged).
//  blocks [P1_BLOCKS, +MLP_BLOCKS): node MLP (4 lanes/node) with weights
//    stored in LDS as PACKED BF16 — halves weight ds_read instructions
//    (224 -> 112 per node); unpack is cheap VALU. Scalar features folded
//    into layer-1 bias. All weight reads are lane-broadcast.
//  HISTORY: 8-lane x 2-node MLP spills ~780MB scratch under all launch
//  bounds (r13/r14/r18) — do not reintroduce. Quarter-buckets (r16) and
//  depth-8 gather (r17) regressed p2.
// ---------------------------------------------------------------------------
__global__ __launch_bounds__(P1_THREADS) void fused_mlp_p1(
    const float* __restrict__ x, const float* __restrict__ scalars,
    const float* __restrict__ W1, const float* __restrict__ b1,
    const float* __restrict__ W2, const float* __restrict__ b2,
    unsigned* __restrict__ y,
    const int* __restrict__ ei,
    unsigned* __restrict__ bbuf,     // [P1_BLOCKS * P1_EPB] sorted packed edges
    int* __restrict__ offs_g)        // [P1_BLOCKS][OFFS_ROW]
{
    __shared__ __align__(16) unsigned char smem[71928];
    const int tid = threadIdx.x;

    if (blockIdx.x < P1_BLOCKS) {
        unsigned* sSE  = (unsigned*)smem;            // 65536 B
        int* cnt       = (int*)(smem + 65536);       // 3128 B (782)
        int* runoff    = (int*)(smem + 68664);       // 3132 B (783)
        int* wsum      = (int*)(smem + 71796);       // 64 B (16)

        const int nbase = blockIdx.x * P1_EPB;
        const int nThis = min(P1_EPB, N_EDGES - nbase);

        for (int i = tid; i < NBKT2; i += P1_THREADS) cnt[i] = 0;
        __syncthreads();

        unsigned pk[P1_EPT];
        int meta[P1_EPT];                 // bkt (10b) | rank<<10 (14b)
        #pragma unroll
        for (int k = 0; k < P1_EPT; ++k) {
            const int idx = tid + k * P1_THREADS;   // coalesced stream
            if (idx < nThis) {
                const int e = nbase + idx;
                const int src = ei[e];
                const int dst = ei[N_EDGES + e];
                const int bkt = dst >> 7;
                const int rank = atomicAdd(&cnt[bkt], 1);
                pk[k]   = (unsigned)src | ((unsigned)(dst & 127) << 17);
                meta[k] = bkt | (rank << 10);
            } else {
                meta[k] = -1;
            }
        }
        __syncthreads();

        // exclusive scan of 782 counts (16 wave-scans + combine)
        const int lane = tid & 63, wid = tid >> 6;
        const int cval = (tid < NBKT2) ? cnt[tid] : 0;
        int a = cval;
        #pragma unroll
        for (int off = 1; off < 64; off <<= 1) {
            const int u = __shfl_up(a, off, 64);
            if (lane >= off) a += u;
        }
        if (lane == 63) wsum[wid] = a;
        __syncthreads();
        if (tid == 0) {
            int r = 0;
            #pragma unroll
            for (int w = 0; w < 16; ++w) { const int t = wsum[w]; wsum[w] = r; r += t; }
        }
        __syncthreads();
        if (tid <= NBKT2) {
            const int bse = wsum[wid] + a - cval;   // tid==NBKT2 -> total == nThis
            runoff[tid] = bse;
            offs_g[blockIdx.x * OFFS_ROW + tid] = bse;
        }
        __syncthreads();

        // scatter into LDS in bucket-sorted order
        #pragma unroll
        for (int k = 0; k < P1_EPT; ++k) {
            if (meta[k] >= 0)
                sSE[runoff[meta[k] & 1023] + (meta[k] >> 10)] = pk[k];
        }
        __syncthreads();

        // stream out: perfectly coalesced uint4
        const uint4* s4 = (const uint4*)sSE;
        uint4* b4 = (uint4*)(bbuf + (size_t)blockIdx.x * P1_EPB);
        for (int i = tid; i < (nThis >> 2); i += P1_THREADS) b4[i] = s4[i];
    } else {
        // ---- mlp: 4 lanes/node, bf16-packed weights in LDS -----------------
        unsigned* sW1p = (unsigned*)smem;            // 768 words  [k][l/2], 3072 B
        unsigned* sW2p = (unsigned*)(smem + 3072);   // 1024 words [l][j/2], 4096 B
        float* sb1f = (float*)(smem + 7168);         // 256 B (scalar-folded bias)
        float* sb2  = (float*)(smem + 7424);         // 128 B
        float* ss   = (float*)(smem + 7552);         // 32 B

        if (tid < F_S)   ss[tid]  = scalars[tid];
        if (tid < F_OUT) sb2[tid] = b2[tid];
        // pack W1 rows 0..23 (x-feature rows) as bf16 pairs along l
        for (int t = tid; t < F_X * (H_DIM / 2); t += P1_THREADS) {
            const int k = t >> 5, p = t & 31;
            sW1p[t] = bf16_rne(W1[k * H_DIM + 2 * p])
                    | (bf16_rne(W1[k * H_DIM + 2 * p + 1]) << 16);
        }
        // pack W2 as bf16 pairs along j
        for (int t = tid; t < H_DIM * (F_OUT / 2); t += P1_THREADS) {
            const int l = t >> 4, p = t & 15;
            sW2p[t] = bf16_rne(W2[l * F_OUT + 2 * p])
                    | (bf16_rne(W2[l * F_OUT + 2 * p + 1]) << 16);
        }
        __syncthreads();
        // fold scalar features into layer-1 bias (f32, from global W1)
        if (tid < H_DIM) {
            float acc = b1[tid];
            #pragma unroll
            for (int j = 0; j < F_S; ++j)
                acc += ss[j] * W1[(F_X + j) * H_DIM + tid];
            sb1f[tid] = acc;
        }
        __syncthreads();

        const int mb = blockIdx.x - P1_BLOCKS;
        const int v = mb * 256 + (tid >> 2);
        const int c = tid & 3;
        if (v >= N_NODES) return;

        // input row: 24 x-features (f32, from global)
        float h[F_X];
        const float4* xr = reinterpret_cast<const float4*>(x + (size_t)v * F_X);
        #pragma unroll
        for (int i = 0; i < F_X / 4; ++i) {
            float4 t = xr[i];
            h[i * 4 + 0] = t.x; h[i * 4 + 1] = t.y;
            h[i * 4 + 2] = t.z; h[i * 4 + 3] = t.w;
        }

        // layer 1: lane owns hid l in [c*16, c*16+16); k = 0..23
        float hid[16];
        {
            const float4* bb = reinterpret_cast<const float4*>(sb1f + c * 16);
            #pragma unroll
            for (int q = 0; q < 4; ++q) {
                const float4 t = bb[q];
                hid[q * 4 + 0] = t.x; hid[q * 4 + 1] = t.y;
                hid[q * 4 + 2] = t.z; hid[q * 4 + 3] = t.w;
            }
        }
        #pragma unroll
        for (int k = 0; k < F_X; ++k) {
            const float hk = h[k];
            // 2 uint4 reads deliver 16 bf16 weights (was 4 float4 reads)
            const uint4* wr = reinterpret_cast<const uint4*>(sW1p + k * 32 + c * 8);
            const uint4 w0 = wr[0], w1 = wr[1];
            const unsigned ww[8] = {w0.x, w0.y, w0.z, w0.w, w1.x, w1.y, w1.z, w1.w};
            #pragma unroll
            for (int p = 0; p < 8; ++p) {
                const float lo = __uint_as_float(ww[p] << 16);
                const float hi = __uint_as_float(ww[p] & 0xFFFF0000u);
                hid[2 * p + 0] = fmaf(hk, lo, hid[2 * p + 0]);
                hid[2 * p + 1] = fmaf(hk, hi, hid[2 * p + 1]);
            }
        }
        #pragma unroll
        for (int l = 0; l < 16; ++l) hid[l] = fmaxf(hid[l], 0.0f);

        // layer 2: lane owns out j in [c*8, c*8+8); shfl hid chunks around
        float op[8];
        #pragma unroll
        for (int t = 0; t < 8; ++t) op[t] = 0.0f;

        #pragma unroll
        for (int d = 0; d < 4; ++d) {
            const int cc = c ^ d;
            float ht[16];
            if (d == 0) {
                #pragma unroll
                for (int t = 0; t < 16; ++t) ht[t] = hid[t];
            } else {
                #pragma unroll
                for (int t = 0; t < 16; ++t) ht[t] = __shfl_xor(hid[t], d);
            }
            const int lbase = cc * 16;
            #pragma unroll
            for (int ll = 0; ll < 16; ++ll) {
                const float hl = ht[ll];
                // 1 uint4 read delivers 8 bf16 weights (was 2 float4 reads)
                const uint4 w = *reinterpret_cast<const uint4*>(
                    sW2p + (lbase + ll) * 16 + c * 4);
                const unsigned ww[4] = {w.x, w.y, w.z, w.w};
                #pragma unroll
                for (int p = 0; p < 4; ++p) {
                    const float lo = __uint_as_float(ww[p] << 16);
                    const float hi = __uint_as_float(ww[p] & 0xFFFF0000u);
                    op[2 * p + 0] = fmaf(hl, lo, op[2 * p + 0]);
                    op[2 * p + 1] = fmaf(hl, hi, op[2 * p + 1]);
                }
            }
        }
        #pragma unroll
        for (int t = 0; t < 8; ++t) op[t] += sb2[c * 8 + t];

        // pack 8 f32 -> 4 uints (bf16 pairs), store 16B; 4 lanes = 64B row
        unsigned pk4[4];
        #pragma unroll
        for (int t = 0; t < 4; ++t)
            pk4[t] = bf16_rne(op[2 * t]) | (bf16_rne(op[2 * t + 1]) << 16);
        uint4* yr = reinterpret_cast<uint4*>(y + (size_t)v * 16 + c * 4);
        *yr = make_uint4(pk4[0], pk4[1], pk4[2], pk4[3]);
    }
}

// ---------------------------------------------------------------------------
// Kernel 2: per-half-bucket aggregation (byte-identical to round 19).
//   a) stage segments into sE (2 threads/segment) + count bins inline
//   b) exclusive scan of 256 bins; scatter src ids into bin-sorted order
//   c) phased gather (low-src bins, barrier, high-src bins), depth-4 pinned
//   d) registers -> global out
// ---------------------------------------------------------------------------
__global__ __launch_bounds__(P2_THREADS) void p2_aggregate(
    const unsigned* __restrict__ bbuf,
    const int* __restrict__ offs_g,
    const unsigned* __restrict__ y,
    float* __restrict__ out)
{
    __shared__ unsigned sE[BCAP_H];        // 18 KB staged edges
    __shared__ unsigned sS[BCAP_H];        // 18 KB sorted src ids
    __shared__ int segsrc[P1_BLOCKS];      // 784 B
    __shared__ int segoff[P1_BLOCKS + 1];  // 788 B
    __shared__ int cnt[2 * HPB];           // 1 KB (doubles as cursor)
    __shared__ int cbase[2 * HPB + 1];     // 1028 B
    __shared__ int wtmp[16];

    const int tid = threadIdx.x;
    const int bkt = blockIdx.x;            // 0..781
    const int lane = tid & 63, wid = tid >> 6;

    // ---- segment table + exclusive scan of 196 lengths -> segoff ----
    int slen = 0;
    if (tid < P1_BLOCKS) {
        const int o0 = offs_g[tid * OFFS_ROW + bkt];
        slen = offs_g[tid * OFFS_ROW + bkt + 1] - o0;
        segsrc[tid] = o0;
    }
    int sa = slen;
    #pragma unroll
    for (int off = 1; off < 64; off <<= 1) {
        const int u = __shfl_up(sa, off, 64);
        if (lane >= off) sa += u;
    }
    if (lane == 63 && wid < 4) wtmp[wid] = sa;
    if (tid < 2 * HPB) cnt[tid] = 0;
    __syncthreads();
    if (tid == 0) {
        int r = 0;
        #pragma unroll
        for (int w = 0; w < 4; ++w) { const int t = wtmp[w]; wtmp[w] = r; r += t; }
        segoff[P1_BLOCKS] = (r < BCAP_H) ? r : BCAP_H;
    }
    __syncthreads();
    if (tid < P1_BLOCKS) segoff[tid] = wtmp[wid] + sa - slen;
    __syncthreads();

    const int nE = segoff[P1_BLOCKS];

    // a) stage: 2 threads per segment, interleaved copy; count bins inline
    {
        const int s = tid >> 1;
        if (s < P1_BLOCKS) {
            const int d0 = segoff[s];
            const int len = ((s + 1 <= P1_BLOCKS) ? segoff[s + 1] : nE) - d0;
            const unsigned* gp = bbuf + (size_t)s * P1_EPB + segsrc[s];
            for (int j = (tid & 1); j < len; j += 2) {
                const int dp = d0 + j;
                if (dp < BCAP_H) {
                    const unsigned w = gp[j];
                    sE[dp] = w;
                    const int bin = (int)((w >> 17) & 127u) * 2
                                  + ((w & 0x1FFFFu) >= SRC_SPLIT);
                    atomicAdd(&cnt[bin], 1);
                }
            }
        }
    }
    __syncthreads();

    // b2) exclusive scan of 256 bins
    int vcnt = 0, a2 = 0;
    if (tid < 2 * HPB) {
        vcnt = cnt[tid];
        a2 = vcnt;
        #pragma unroll
        for (int off = 1; off < 64; off <<= 1) {
            const int u = __shfl_up(a2, off, 64);
            if (lane >= off) a2 += u;
        }
        if (lane == 63) wtmp[8 + wid] = a2;
    }
    __syncthreads();
    if (tid == 0) {
        int r = 0;
        #pragma unroll
        for (int w = 0; w < 4; ++w) { const int t = wtmp[8 + w]; wtmp[8 + w] = r; r += t; }
        cbase[2 * HPB] = r;
    }
    __syncthreads();
    if (tid < 2 * HPB) cbase[tid] = wtmp[8 + wid] + a2 - vcnt;
    __syncthreads();
    if (tid < 2 * HPB) cnt[tid] = cbase[tid];   // cursor
    __syncthreads();

    // b3) scatter src ids into bin-sorted order
    for (int i = tid; i < nE; i += P2_THREADS) {
        const unsigned w = sE[i];
        const unsigned src = w & 0x1FFFFu;
        const int bin = (int)((w >> 17) & 127u) * 2 + (src >= SRC_SPLIT);
        const int pos = atomicAdd(&cnt[bin], 1);
        if (pos < BCAP_H) sS[pos] = src;
    }
    __syncthreads();

    // c) phased gather: 4-lane group g owns node g; lane c = uint4 chunk c
    const int g = tid >> 2;     // 0..127
    const int c = tid & 3;

    float acc[8];
    #pragma unroll
    for (int k = 0; k < 8; ++k) acc[k] = 0.0f;

    #pragma unroll
    for (int ph = 0; ph < 2; ++ph) {
        int beg = cbase[2 * g + ph];
        int end = cbase[2 * g + ph + 1];
        if (beg > BCAP_H) beg = BCAP_H;
        if (end > BCAP_H) end = BCAP_H;

        int i = beg;
        for (; i + 4 <= end; i += 4) {
            unsigned s[4];
            #pragma unroll
            for (int j = 0; j < 4; ++j) s[j] = sS[i + j];

            uint4 q[4];
            #pragma unroll
            for (int j = 0; j < 4; ++j)
                q[j] = reinterpret_cast<const uint4*>(y + (size_t)s[j] * 16)[c];

            __builtin_amdgcn_sched_barrier(0);   // keep 4 loads in flight

            #pragma unroll
            for (int j = 0; j < 4; ++j) {
                const unsigned qq[4] = {q[j].x, q[j].y, q[j].z, q[j].w};
                #pragma unroll
                for (int k = 0; k < 4; ++k) {
                    acc[2 * k + 0] += __uint_as_float(qq[k] << 16);
                    acc[2 * k + 1] += __uint_as_float(qq[k] & 0xFFFF0000u);
                }
            }
        }
        for (; i < end; ++i) {
            const uint4 q = reinterpret_cast<const uint4*>(y + (size_t)sS[i] * 16)[c];
            const unsigned qq[4] = {q.x, q.y, q.z, q.w};
            #pragma unroll
            for (int k = 0; k < 4; ++k) {
                acc[2 * k + 0] += __uint_as_float(qq[k] << 16);
                acc[2 * k + 1] += __uint_as_float(qq[k] & 0xFFFF0000u);
            }
        }
        if (ph == 0) __syncthreads();   // block-wide phase boundary
    }

    // d) write out: lane owns floats [c*8, c*8+8) of row v
    const int v = bkt * HPB + g;
    if (v < N_NODES) {
        float4* op = reinterpret_cast<float4*>(out + (size_t)v * F_OUT + c * 8);
        op[0] = make_float4(acc[0], acc[1], acc[2], acc[3]);
        op[1] = make_float4(acc[4], acc[5], acc[6], acc[7]);
    }
}

extern "C" void kernel_launch(void* const* d_in, const int* in_sizes, int n_in,
                              void* d_out, int out_size, void* d_ws, size_t ws_size,
                              hipStream_t stream) {
    const float* x       = (const float*)d_in[0];
    const float* scalars = (const float*)d_in[1];
    const int*   ei      = (const int*)d_in[2];
    const float* W1      = (const float*)d_in[3];
    const float* b1      = (const float*)d_in[4];
    const float* W2      = (const float*)d_in[5];
    const float* b2      = (const float*)d_in[6];
    float* out = (float*)d_out;

    // Workspace layout (16B aligned), total ~19.9 MB
    char* ws = (char*)d_ws;
    unsigned* y      = (unsigned*)ws;                    //  6,400,000 B
    unsigned* bbuf   = (unsigned*)(ws + 6400000);        // 12,845,056 B (196*16384*4)
    int*      offs_g = (int*)(ws + 19245056);            //    613,872 B (196*783*4)

    // 1) fused: edge partition (blocks 0..195) + node MLP (blocks 196..586)
    fused_mlp_p1<<<P1_BLOCKS + MLP_BLOCKS, P1_THREADS, 0, stream>>>(
        x, scalars, W1, b1, W2, b2, y, ei, bbuf, offs_g);

    // 2) per-half-bucket stage + sort + phased gather + write (782 blocks)
    p2_aggregate<<<NBKT2, P2_THREADS, 0, stream>>>(bbuf, offs_g, y, out);
}